// Round 3
// baseline (638.223 us; speedup 1.0000x reference)
//
#include <hip/hip_runtime.h>
#include <stdint.h>

typedef unsigned short u16;
typedef __bf16 bf16x8 __attribute__((ext_vector_type(8)));
typedef float f32x4 __attribute__((ext_vector_type(4)));
typedef unsigned short u16x8 __attribute__((ext_vector_type(8)));

#define B_ROWS 4096
#define H_DIM  2048
#define K_DIM  4096   // concat K = IN + H
#define N_DIM  8192   // 4 gates * H, interleaved n' = 4*j + g

__device__ __forceinline__ u16 f2b(float f) {
  union { float f; unsigned int i; } v; v.f = f;
  unsigned int i = v.i;
  return (u16)((i + 0x7fffu + ((i >> 16) & 1u)) >> 16);  // RNE
}
__device__ __forceinline__ float sigmoidf_(float x) { return 1.0f / (1.0f + __expf(-x)); }
__device__ __forceinline__ float tanhf_(float x)    { return 1.0f - 2.0f / (__expf(2.0f * x) + 1.0f); }

// async global->LDS, 16B per lane. LDS dest = wave-uniform base + lane*16.
__device__ __forceinline__ void glds16(const u16* g, u16* l) {
  __builtin_amdgcn_global_load_lds(
      (__attribute__((address_space(1))) void*)(g),
      (__attribute__((address_space(3))) void*)(l), 16, 0, 0);
}

struct WPtrs { const float* p[8]; };  // w_xi,w_xf,w_xo,w_xc,w_hi,w_hf,w_ho,w_hc (fp32)

// ---------------- prep 0: interleave biases: biasI[4*j+g] = b_g[j] (fp32)
__global__ __launch_bounds__(256) void prep_bias(const float* __restrict__ Bi,
                                                 const float* __restrict__ Bf,
                                                 const float* __restrict__ Bo,
                                                 const float* __restrict__ Bc,
                                                 float* __restrict__ biasI) {
  const int j = blockIdx.x * 256 + threadIdx.x;
  float4 v;
  v.x = Bi[j]; v.y = Bf[j]; v.z = Bo[j]; v.w = Bc[j];
  *(float4*)(biasI + (size_t)j * 4) = v;
}

// ---------------- prep 1: Abf[b][k] = bf16(concat(x,h)[b][k])
__global__ __launch_bounds__(256) void convert_A(const float* __restrict__ X,
                                                 const float* __restrict__ Hs,
                                                 u16* __restrict__ Abf) {
  const int idx = blockIdx.x * 256 + threadIdx.x;   // 8 elems per thread
  const int b = idx >> 9;
  const int c = (idx & 511) * 8;
  const float* src = (c < H_DIM) ? (X + (size_t)b * H_DIM + c)
                                 : (Hs + (size_t)b * H_DIM + (c - H_DIM));
  float4 v0 = *(const float4*)(src);
  float4 v1 = *(const float4*)(src + 4);
  u16x8 o;
  o[0] = f2b(v0.x); o[1] = f2b(v0.y); o[2] = f2b(v0.z); o[3] = f2b(v0.w);
  o[4] = f2b(v1.x); o[5] = f2b(v1.y); o[6] = f2b(v1.z); o[7] = f2b(v1.w);
  *(u16x8*)(Abf + (size_t)b * K_DIM + c) = o;
}

// ---------------- prep 2: Wt[n'][k] = bf16(W[k][n]), n' = 4*j + g, k = s*2048+kappa
// LDS row stride 70 u16: read-phase row step = 8*70*2B = 1120B -> bank step 24,
// {0,24,16,8} x jr/2 -> <=4-way (was 8-way at stride 72).
__global__ __launch_bounds__(256) void transpose_w(WPtrs wp, u16* __restrict__ Wt) {
  __shared__ u16 tile[64][70];
  const int jt = blockIdx.x;        // j tile (64 wide)
  const int kt = blockIdx.y;        // kappa tile (64 tall)
  const int z  = blockIdx.z;        // s*4+g
  const int s = z >> 2, g = z & 3;
  const float* __restrict__ w = wp.p[z];
  const int tid = threadIdx.x;
  const int j0 = jt * 64, k0 = kt * 64;

  const int c4 = (tid & 15) * 4;
  const int r0 = tid >> 4;          // 0..15
#pragma unroll
  for (int it = 0; it < 4; ++it) {
    int r = r0 + it * 16;
    float4 v = *(const float4*)(w + (size_t)(k0 + r) * H_DIM + j0 + c4);
    tile[r][c4 + 0] = f2b(v.x);
    tile[r][c4 + 1] = f2b(v.y);
    tile[r][c4 + 2] = f2b(v.z);
    tile[r][c4 + 3] = f2b(v.w);
  }
  __syncthreads();

  const int cc = (tid & 7) * 8;     // kappa chunk
  const int jr0 = tid >> 3;         // 0..31
#pragma unroll
  for (int it = 0; it < 2; ++it) {
    int jr = jr0 + it * 32;
    u16x8 v;
#pragma unroll
    for (int i = 0; i < 8; ++i) v[i] = tile[cc + i][jr];
    size_t orow = (size_t)(4 * (j0 + jr) + g);          // interleaved gate dim
    *(u16x8*)(Wt + orow * K_DIM + (size_t)(s * H_DIM + k0 + cc)) = v;
  }
}

// ---------------- fused GEMM + LSTM epilogue
// gates[b][n'] = sum_k Abf[b][k] * Wt[n'][k]; then per (b,j): i,f,o,g adjacent
// (n' = 4j+g) -> LDS round-trip per mi-pass, activations in fp32, write h/c.
__global__ __launch_bounds__(256) void gemm_lstm(const u16* __restrict__ A,
                                                 const u16* __restrict__ Wt,
                                                 const float* __restrict__ biasI,
                                                 const float* __restrict__ Cin,
                                                 float* __restrict__ Out) {
  __shared__ __align__(16) unsigned char smem[132 * 32 * 4];  // 16896B >= 16384 staging
  u16* sA = (u16*)smem;
  u16* sB = (u16*)(smem + 8192);
  float* L = (float*)smem;                                    // epilogue scratch [32][132]

  const int tid = threadIdx.x;
  const int wave = tid >> 6, lane = tid & 63;
  const int bm = blockIdx.x & 31;   // 32 M-tiles
  const int bn = blockIdx.x >> 5;   // 64 N-tiles
  const int wr = (wave >> 1) * 64;
  const int wc = (wave & 1) * 64;

  // staging: wave w owns 1KB chunks {2w, 2w+1}; lane lands at chunk_base + lane*16B
  const int c0 = wave * 2;
  const int row0 = c0 * 16 + (lane >> 2);
  const int row1 = row0 + 16;
  const int kc0 = (lane & 3) ^ ((row0 >> 1) & 3);
  const int kc1 = (lane & 3) ^ ((row1 >> 1) & 3);
  const size_t gA0 = (size_t)(bm * 128 + row0) * K_DIM + kc0 * 8;
  const size_t gA1 = (size_t)(bm * 128 + row1) * K_DIM + kc1 * 8;
  const size_t gB0 = (size_t)(bn * 128 + row0) * K_DIM + kc0 * 8;
  const size_t gB1 = (size_t)(bn * 128 + row1) * K_DIM + kc1 * 8;
  u16* ldsA0 = sA + c0 * 512;
  u16* ldsA1 = sA + (c0 + 1) * 512;
  u16* ldsB0 = sB + c0 * 512;
  u16* ldsB1 = sB + (c0 + 1) * 512;

  const int q = lane >> 4;
  int aOff[4], bOff[4];
#pragma unroll
  for (int i = 0; i < 4; ++i) {
    int ra = wr + i * 16 + (lane & 15);
    aOff[i] = ra * 32 + ((q ^ ((ra >> 1) & 3)) * 8);
    int rb = wc + i * 16 + (lane & 15);
    bOff[i] = rb * 32 + ((q ^ ((rb >> 1) & 3)) * 8);
  }

  f32x4 acc[4][4] = {};

  for (int kt = 0; kt < K_DIM / 32; ++kt) {
    const int kg = kt * 32;
    __syncthreads();
    glds16(A + gA0 + kg, ldsA0);
    glds16(A + gA1 + kg, ldsA1);
    glds16(Wt + gB0 + kg, ldsB0);
    glds16(Wt + gB1 + kg, ldsB1);
    __syncthreads();

    bf16x8 af[4], bf[4];
#pragma unroll
    for (int i = 0; i < 4; ++i) af[i] = *reinterpret_cast<const bf16x8*>(sA + aOff[i]);
#pragma unroll
    for (int i = 0; i < 4; ++i) bf[i] = *reinterpret_cast<const bf16x8*>(sB + bOff[i]);
#pragma unroll
    for (int mi = 0; mi < 4; ++mi)
#pragma unroll
      for (int ni = 0; ni < 4; ++ni)
        acc[mi][ni] = __builtin_amdgcn_mfma_f32_16x16x32_bf16(af[mi], bf[ni], acc[mi][ni], 0, 0, 0);
  }

  // ---- fused epilogue, 4 passes (one per mi), 32 rows x 128 cols each ----
  // C/D layout: col = lane&15 (n'_loc within 16-tile), row = (lane>>4)*4 + r.
  const int slotb = (wave >> 1) * 16 + (lane >> 4) * 4;       // write slot base
  const int rslot = tid >> 3;                                 // read: 0..31
  const int j0l   = (tid & 7) * 4;                            // read: local j, 4 per thread
  const int jg    = bn * 32 + j0l;
  const size_t cbase = (size_t)B_ROWS * H_DIM;                // c_t offset in Out

#pragma unroll
  for (int mi = 0; mi < 4; ++mi) {
    __syncthreads();    // previous pass reads (or K-loop MFMA LDS use) done
#pragma unroll
    for (int ni = 0; ni < 4; ++ni) {
      int colb = wc + ni * 16 + (lane & 15);
#pragma unroll
      for (int r = 0; r < 4; ++r)
        L[(size_t)(slotb + r) * 132 + colb] = acc[mi][ni][r];
    }
    __syncthreads();

    const int row_glob = bm * 128 + (rslot >> 4) * 64 + mi * 16 + (rslot & 15);
    float4 cin4 = *(const float4*)(Cin + (size_t)row_glob * H_DIM + jg);
    float ce[4] = {cin4.x, cin4.y, cin4.z, cin4.w};
    float he[4], cte[4];
#pragma unroll
    for (int e = 0; e < 4; ++e) {
      float4 g4 = *(const float4*)&L[(size_t)rslot * 132 + (j0l + e) * 4];
      float4 b4 = *(const float4*)(biasI + (size_t)(jg + e) * 4);
      float it = sigmoidf_(g4.x + b4.x);
      float ft = sigmoidf_(g4.y + b4.y);
      float ot = sigmoidf_(g4.z + b4.z);
      float gt = tanhf_(g4.w + b4.w);
      float ct = ce[e] * ft + it * gt;
      he[e]  = ot * tanhf_(ct);
      cte[e] = ct;
    }
    float4 hv;  hv.x = he[0];  hv.y = he[1];  hv.z = he[2];  hv.w = he[3];
    float4 cv;  cv.x = cte[0]; cv.y = cte[1]; cv.z = cte[2]; cv.w = cte[3];
    *(float4*)(Out + (size_t)row_glob * H_DIM + jg) = hv;
    *(float4*)(Out + cbase + (size_t)row_glob * H_DIM + jg) = cv;
  }
}

extern "C" void kernel_launch(void* const* d_in, const int* in_sizes, int n_in,
                              void* d_out, int out_size, void* d_ws, size_t ws_size,
                              hipStream_t stream) {
  const float* X   = (const float*)d_in[0];
  const float* Hs  = (const float*)d_in[1];
  const float* Cin = (const float*)d_in[2];
  WPtrs wp;
  for (int i = 0; i < 8; ++i) wp.p[i] = (const float*)d_in[3 + i];
  const float* Bi = (const float*)d_in[11];
  const float* Bf = (const float*)d_in[12];
  const float* Bo = (const float*)d_in[13];
  const float* Bc = (const float*)d_in[14];

  u16* Wt      = (u16*)d_ws;                        // [8192][4096] bf16 = 67.1 MB
  u16* Abf     = Wt + (size_t)N_DIM * K_DIM;        // [4096][4096] bf16 = 33.6 MB
  float* biasI = (float*)(Abf + (size_t)B_ROWS * K_DIM);  // [8192] fp32 = 32 KB
  float* Out   = (float*)d_out;

  prep_bias<<<H_DIM / 256, 256, 0, stream>>>(Bi, Bf, Bo, Bc, biasI);
  convert_A<<<(B_ROWS * K_DIM / 8) / 256, 256, 0, stream>>>(X, Hs, Abf);
  transpose_w<<<dim3(32, 32, 8), 256, 0, stream>>>(wp, Wt);
  gemm_lstm<<<32 * 64, 256, 0, stream>>>(Abf, Wt, biasI, Cin, Out);
}

// Round 4
// 584.380 us; speedup vs baseline: 1.0921x; 1.0921x over previous
//
#include <hip/hip_runtime.h>
#include <stdint.h>

typedef unsigned short u16;
typedef __bf16 bf16x8 __attribute__((ext_vector_type(8)));
typedef float f32x4 __attribute__((ext_vector_type(4)));
typedef unsigned short u16x8 __attribute__((ext_vector_type(8)));
typedef unsigned short u16x4 __attribute__((ext_vector_type(4)));

#define B_ROWS 4096
#define H_DIM  2048
#define K_DIM  4096   // concat K = IN + H
#define N_DIM  8192   // 4 gates * H, n = g*2048 + j

__device__ __forceinline__ u16 f2b(float f) {
  union { float f; unsigned int i; } v; v.f = f;
  unsigned int i = v.i;
  return (u16)((i + 0x7fffu + ((i >> 16) & 1u)) >> 16);  // RNE
}
__device__ __forceinline__ float b2f(u16 u) {
  union { unsigned int i; float f; } v; v.i = ((unsigned int)u) << 16; return v.f;
}
__device__ __forceinline__ float sigmoidf_(float x) { return 1.0f / (1.0f + __expf(-x)); }
__device__ __forceinline__ float tanhf_(float x)    { return 1.0f - 2.0f / (__expf(2.0f * x) + 1.0f); }

// async global->LDS, 16B per lane. LDS dest = wave-uniform base + lane*16.
__device__ __forceinline__ void glds16(const u16* g, u16* l) {
  __builtin_amdgcn_global_load_lds(
      (__attribute__((address_space(1))) void*)(g),
      (__attribute__((address_space(3))) void*)(l), 16, 0, 0);
}

struct WPtrs { const float* p[8]; };  // w_xi,w_xf,w_xo,w_xc,w_hi,w_hf,w_ho,w_hc (fp32)

// ---------------- prep: z<8 -> weight transpose+convert, z>=8 -> A concat+convert.
// Transpose LDS tile [64][65]: 65 = 1 mod 32, both phases hit bank (r+c) mod 32,
// 64 lanes span all 32 banks 2-way -> free (m136). Round-2 stride-72 was 16-way.
__global__ __launch_bounds__(256) void prep_all(WPtrs wp,
                                                const float* __restrict__ X,
                                                const float* __restrict__ Hs,
                                                u16* __restrict__ Wt,
                                                u16* __restrict__ Abf) {
  __shared__ float tile[64][65];
  const int z = blockIdx.z;
  const int tid = threadIdx.x;
  if (z < 8) {
    const int s = z >> 2, g = z & 3;
    const float* __restrict__ w = wp.p[z];
    const int j0 = blockIdx.x * 64, k0 = blockIdx.y * 64;

    const int c4 = (tid & 15) * 4;
    const int r0 = tid >> 4;          // 0..15
#pragma unroll
    for (int it = 0; it < 4; ++it) {
      int r = r0 + it * 16;
      float4 v = *(const float4*)(w + (size_t)(k0 + r) * H_DIM + j0 + c4);
      tile[r][c4 + 0] = v.x;
      tile[r][c4 + 1] = v.y;
      tile[r][c4 + 2] = v.z;
      tile[r][c4 + 3] = v.w;
    }
    __syncthreads();

    const int cc = (tid & 7) * 8;     // kappa chunk
    const int jr0 = tid >> 3;         // 0..31
#pragma unroll
    for (int it = 0; it < 2; ++it) {
      int jr = jr0 + it * 32;
      u16x8 v;
#pragma unroll
      for (int i = 0; i < 8; ++i) v[i] = f2b(tile[cc + i][jr]);
      size_t orow = (size_t)(g * H_DIM + j0 + jr);
      *(u16x8*)(Wt + orow * K_DIM + (size_t)(s * H_DIM + k0 + cc)) = v;
    }
  } else {
    // A-convert: 2048 blocks (z=8,9), 4 chunks of 8 elems per thread
    const int cid = (z - 8) * 1024 + blockIdx.y * 32 + blockIdx.x;   // 0..2047
#pragma unroll
    for (int t = 0; t < 4; ++t) {
      const size_t chunk = (size_t)cid * 1024 + t * 256 + tid;       // 8-elem chunk id
      const int b = (int)(chunk >> 9);
      const int c = ((int)chunk & 511) * 8;
      const float* src = (c < H_DIM) ? (X + (size_t)b * H_DIM + c)
                                     : (Hs + (size_t)b * H_DIM + (c - H_DIM));
      float4 v0 = *(const float4*)(src);
      float4 v1 = *(const float4*)(src + 4);
      u16x8 o;
      o[0] = f2b(v0.x); o[1] = f2b(v0.y); o[2] = f2b(v0.z); o[3] = f2b(v0.w);
      o[4] = f2b(v1.x); o[5] = f2b(v1.y); o[6] = f2b(v1.z); o[7] = f2b(v1.w);
      *(u16x8*)(Abf + chunk * 8) = o;
    }
  }
}

// ---------------- main GEMM (round-2 proven): gates[b][n] = sum_k Abf[b][k] * Wt[n][k]
// m97 recipe: 128x128 tile, BK=32, 4 waves each 64x64 (4x4 frags of 16x16x32),
// global_load_lds width=16 both operands, XOR swizzle kc ^= (row>>1)&3.
__global__ __launch_bounds__(256) void gemm_gates(const u16* __restrict__ A,
                                                  const u16* __restrict__ Wt,
                                                  u16* __restrict__ gates) {
  __shared__ __align__(16) u16 sA[128 * 32];
  __shared__ __align__(16) u16 sB[128 * 32];
  const int tid = threadIdx.x;
  const int wave = tid >> 6, lane = tid & 63;
  const int bm = blockIdx.x & 31;   // 32 M-tiles
  const int bn = blockIdx.x >> 5;   // 64 N-tiles
  const int wr = (wave >> 1) * 64;
  const int wc = (wave & 1) * 64;

  // staging: wave w owns 1KB chunks {2w, 2w+1}; lane lands at chunk_base + lane*16B
  const int c0 = wave * 2;
  const int row0 = c0 * 16 + (lane >> 2);
  const int row1 = row0 + 16;
  const int kc0 = (lane & 3) ^ ((row0 >> 1) & 3);
  const int kc1 = (lane & 3) ^ ((row1 >> 1) & 3);
  const size_t gA0 = (size_t)(bm * 128 + row0) * K_DIM + kc0 * 8;
  const size_t gA1 = (size_t)(bm * 128 + row1) * K_DIM + kc1 * 8;
  const size_t gB0 = (size_t)(bn * 128 + row0) * K_DIM + kc0 * 8;
  const size_t gB1 = (size_t)(bn * 128 + row1) * K_DIM + kc1 * 8;
  u16* ldsA0 = sA + c0 * 512;
  u16* ldsA1 = sA + (c0 + 1) * 512;
  u16* ldsB0 = sB + c0 * 512;
  u16* ldsB1 = sB + (c0 + 1) * 512;

  // fragment LDS offsets (u16 units): lane holds row (lane&15), k-chunk q=lane>>4
  const int q = lane >> 4;
  int aOff[4], bOff[4];
#pragma unroll
  for (int i = 0; i < 4; ++i) {
    int ra = wr + i * 16 + (lane & 15);
    aOff[i] = ra * 32 + ((q ^ ((ra >> 1) & 3)) * 8);
    int rb = wc + i * 16 + (lane & 15);
    bOff[i] = rb * 32 + ((q ^ ((rb >> 1) & 3)) * 8);
  }

  f32x4 acc[4][4] = {};

  for (int kt = 0; kt < K_DIM / 32; ++kt) {
    const int kg = kt * 32;
    __syncthreads();                            // LDS safe to overwrite
    glds16(A + gA0 + kg, ldsA0);
    glds16(A + gA1 + kg, ldsA1);
    glds16(Wt + gB0 + kg, ldsB0);
    glds16(Wt + gB1 + kg, ldsB1);
    __syncthreads();                            // drains vmcnt for glds

    bf16x8 af[4], bf[4];
#pragma unroll
    for (int i = 0; i < 4; ++i) af[i] = *reinterpret_cast<const bf16x8*>(sA + aOff[i]);
#pragma unroll
    for (int i = 0; i < 4; ++i) bf[i] = *reinterpret_cast<const bf16x8*>(sB + bOff[i]);
#pragma unroll
    for (int mi = 0; mi < 4; ++mi)
#pragma unroll
      for (int ni = 0; ni < 4; ++ni)
        acc[mi][ni] = __builtin_amdgcn_mfma_f32_16x16x32_bf16(af[mi], bf[ni], acc[mi][ni], 0, 0, 0);
  }

  // C/D layout (m89-verified): col = lane&15, row = (lane>>4)*4 + reg
  const int rbase = bm * 128 + wr + (lane >> 4) * 4;
  const int cbase = bn * 128 + wc + (lane & 15);
#pragma unroll
  for (int mi = 0; mi < 4; ++mi) {
#pragma unroll
    for (int ni = 0; ni < 4; ++ni) {
      size_t base = (size_t)(rbase + mi * 16) * N_DIM + (size_t)(cbase + ni * 16);
#pragma unroll
      for (int r = 0; r < 4; ++r)
        gates[base + (size_t)r * N_DIM] = f2b(acc[mi][ni][r]);
    }
  }
}

// ---------------- epilogue: bias + nonlinearity + cell update (fp32 out)
__global__ __launch_bounds__(256) void lstm_epilogue(
    const u16* __restrict__ gates, const float* __restrict__ Cin,
    const float* __restrict__ Bi, const float* __restrict__ Bf,
    const float* __restrict__ Bo, const float* __restrict__ Bc,
    float* __restrict__ Out) {
  const int idx = blockIdx.x * 256 + threadIdx.x;   // 4 elems per thread
  const int b = idx >> 9;                           // 512 chunks of 4 per 2048-col row
  const int j = (idx & 511) * 4;
  const size_t gbase = (size_t)b * N_DIM + j;
  u16x4 iv = *(const u16x4*)(gates + gbase);
  u16x4 fv = *(const u16x4*)(gates + gbase + 2048);
  u16x4 ov = *(const u16x4*)(gates + gbase + 4096);
  u16x4 gv = *(const u16x4*)(gates + gbase + 6144);
  float4 cv  = *(const float4*)(Cin + (size_t)b * H_DIM + j);
  float4 biv = *(const float4*)(Bi + j);
  float4 bfv = *(const float4*)(Bf + j);
  float4 bov = *(const float4*)(Bo + j);
  float4 bcv = *(const float4*)(Bc + j);
  float ce[4] = {cv.x, cv.y, cv.z, cv.w};
  float bie[4] = {biv.x, biv.y, biv.z, biv.w};
  float bfe[4] = {bfv.x, bfv.y, bfv.z, bfv.w};
  float boe[4] = {bov.x, bov.y, bov.z, bov.w};
  float bce[4] = {bcv.x, bcv.y, bcv.z, bcv.w};
  float4 hv, ctv;
  float he[4], cte[4];
#pragma unroll
  for (int e = 0; e < 4; ++e) {
    float it = sigmoidf_(b2f(iv[e]) + bie[e]);
    float ft = sigmoidf_(b2f(fv[e]) + bfe[e]);
    float ot = sigmoidf_(b2f(ov[e]) + boe[e]);
    float gt = tanhf_(b2f(gv[e]) + bce[e]);
    float ct = ce[e] * ft + it * gt;
    he[e] = ot * tanhf_(ct);
    cte[e] = ct;
  }
  hv.x = he[0]; hv.y = he[1]; hv.z = he[2]; hv.w = he[3];
  ctv.x = cte[0]; ctv.y = cte[1]; ctv.z = cte[2]; ctv.w = cte[3];
  *(float4*)(Out + (size_t)b * H_DIM + j) = hv;                                       // h_t
  *(float4*)(Out + (size_t)B_ROWS * H_DIM + (size_t)b * H_DIM + j) = ctv;             // c_t
}

extern "C" void kernel_launch(void* const* d_in, const int* in_sizes, int n_in,
                              void* d_out, int out_size, void* d_ws, size_t ws_size,
                              hipStream_t stream) {
  const float* X   = (const float*)d_in[0];
  const float* Hs  = (const float*)d_in[1];
  const float* Cin = (const float*)d_in[2];
  WPtrs wp;
  for (int i = 0; i < 8; ++i) wp.p[i] = (const float*)d_in[3 + i];
  const float* Bi = (const float*)d_in[11];
  const float* Bf = (const float*)d_in[12];
  const float* Bo = (const float*)d_in[13];
  const float* Bc = (const float*)d_in[14];

  u16* Wt    = (u16*)d_ws;                        // [8192][4096] bf16 = 67.1 MB
  u16* Abf   = Wt + (size_t)N_DIM * K_DIM;        // [4096][4096] bf16 = 33.6 MB
  u16* gates = Abf + (size_t)B_ROWS * K_DIM;      // [4096][8192] bf16 = 67.1 MB
  float* Out = (float*)d_out;

  prep_all<<<dim3(32, 32, 10), 256, 0, stream>>>(wp, X, Hs, Wt, Abf);
  gemm_gates<<<32 * 64, 256, 0, stream>>>(Abf, Wt, gates);
  lstm_epilogue<<<(B_ROWS * H_DIM / 4) / 256, 256, 0, stream>>>(gates, Cin, Bi, Bf, Bo, Bc, Out);
}